// Round 3
// baseline (431.943 us; speedup 1.0000x reference)
//
#include <hip/hip_runtime.h>
#include <math.h>

// GRU-D, diagonal weights: independent scalar recurrence per (b,f) over T.
// R4: fix R3's data hazard (loads for chunk k+2 were issued into the SAME
// register buffer computec(k) was about to read -> clobbered inputs, absmax
// 0.25). Correct structure is R2's compute-then-load phase order, plus
// sched_barrier(0) after each phase so the machine scheduler cannot sink the
// prefetch load cluster to its uses (which is what dissolved R2's double
// buffer: VGPR=68, latency-bound at 185us). Anti-dependences prevent illegal
// hoisting within a phase, so compute(k); load(k+2); <fence> is hazard-free
// and keeps 24-48 loads in flight across every phase boundary. One thread
// per (b,f) chain; all global accesses fully-coalesced 256B wave
// transactions; no LDS, no barriers, no loader waves.

#define TT 512
#define BB 256
#define FF 256
#define BF (BB * FF)        // elements per time step per array
#define CH 8                // steps per register chunk
#define NCH (TT / CH)       // 64 chunks

__device__ __forceinline__ float fast_sigmoid(float x) {
    return __builtin_amdgcn_rcpf(1.0f + __expf(-x));
}
__device__ __forceinline__ float fast_tanh(float x) {
    return fmaf(-2.0f, __builtin_amdgcn_rcpf(1.0f + __expf(2.0f * x)), 1.0f);
}

__global__ __launch_bounds__(256, 1) void grud_kernel(
    const float* __restrict__ X, const float* __restrict__ Mask,
    const float* __restrict__ Delta,
    const float* __restrict__ x_mean,
    const float* __restrict__ w_dg_x, const float* __restrict__ b_dg_x,
    const float* __restrict__ w_dg_h, const float* __restrict__ b_dg_h,
    const float* __restrict__ w_xz, const float* __restrict__ u_hz,
    const float* __restrict__ b_z,
    const float* __restrict__ w_xr, const float* __restrict__ u_hr,
    const float* __restrict__ b_r,
    const float* __restrict__ w_xh, const float* __restrict__ u_hh,
    const float* __restrict__ v_mh, const float* __restrict__ b_h,
    float* __restrict__ out)
{
    const int f = threadIdx.x;          // 0..255 : feature index
    const int b = blockIdx.x;           // batch index

    const size_t base = (size_t)b * FF + f;
    const float* __restrict__ px = X     + base;
    const float* __restrict__ pm = Mask  + base;
    const float* __restrict__ pd = Delta + base;
    float* __restrict__ ob = out + (size_t)b * TT * FF + f;

    // per-feature parameters (L2-resident, coalesced)
    const float xm  = x_mean[f];
    const float wdx = w_dg_x[f], bdx = b_dg_x[f];
    const float wdh = w_dg_h[f], bdh = b_dg_h[f];
    const float wxz = w_xz[f],   uhz = u_hz[f], bz = b_z[f];
    const float wxr = w_xr[f],   uhr = u_hr[f], br = b_r[f];
    const float wxh = w_xh[f],   uhh = u_hh[f];
    const float vmh = v_mh[f],   bh  = b_h[f];

    // two register chunk-buffers (2 * 3 * 8 = 48 VGPRs of payload)
    float ax[CH], am[CH], ad[CH];
    float ex[CH], em[CH], ed[CH];
    float h = 0.0f;

    auto loadc = [&](float (&dx)[CH], float (&dm)[CH], float (&dd)[CH], int k0) {
        const size_t o = (size_t)k0 * CH * BF;
        #pragma unroll
        for (int s = 0; s < CH; ++s) dx[s] = px[o + (size_t)s * BF];
        #pragma unroll
        for (int s = 0; s < CH; ++s) dm[s] = pm[o + (size_t)s * BF];
        #pragma unroll
        for (int s = 0; s < CH; ++s) dd[s] = pd[o + (size_t)s * BF];
    };

    auto computec = [&](float (&dx)[CH], float (&dm)[CH], float (&dd)[CH], int k0) {
        float* op = ob + (size_t)k0 * CH * FF;
        #pragma unroll
        for (int s = 0; s < CH; ++s) {
            float x = dx[s], m = dm[s], d = dd[s];
            float gx = __expf(-fmaxf(0.0f, fmaf(wdx, d, bdx)));
            float gh = __expf(-fmaxf(0.0f, fmaf(wdh, d, bdh)));
            float xhat = fmaf(gx, x, (1.0f - gx) * xm);
            x = fmaf(m, x, (1.0f - m) * xhat);
            h = gh * h;
            float z  = fast_sigmoid(fmaf(wxz, x, fmaf(uhz, h, bz)));
            float r  = fast_sigmoid(fmaf(wxr, x, fmaf(uhr, h, br)));
            float ht = fast_tanh(fmaf(wxh, x, fmaf(uhh, r * h, fmaf(vmh, m, bh))));
            h = fmaf(z, ht - h, h);               // (1-z)*h + z*ht
            __builtin_nontemporal_store(h, op + (size_t)s * FF);
        }
    };

    // prologue: chunks 0 and 1 in flight before any compute
    loadc(ax, am, ad, 0);
    loadc(ex, em, ed, 1);
    __builtin_amdgcn_sched_barrier(0);

    // steady state, schedule pinned per phase:
    //   compute(k) ; issue(k+2) | fence | compute(k+1) ; issue(k+3) | fence
    // Loads issued at the end of phase k are consumed at the start of phase
    // k+2 -> always one full compute phase (~800 cy) of latency cover, and
    // the fence stops the scheduler from sinking them to their uses.
    for (int k = 0; k < NCH - 2; k += 2) {
        computec(ax, am, ad, k);
        loadc(ax, am, ad, k + 2);
        __builtin_amdgcn_sched_barrier(0);
        computec(ex, em, ed, k + 1);
        loadc(ex, em, ed, k + 3);       // k <= NCH-4 -> k+3 <= NCH-1, valid
        __builtin_amdgcn_sched_barrier(0);
    }
    // tail: chunks NCH-2 (in ax), NCH-1 (in ex) already resident
    computec(ax, am, ad, NCH - 2);
    computec(ex, em, ed, NCH - 1);

    // second output: last hidden state [B, H]
    out[(size_t)BB * TT * FF + (size_t)b * FF + f] = h;
}

extern "C" void kernel_launch(void* const* d_in, const int* in_sizes, int n_in,
                              void* d_out, int out_size, void* d_ws, size_t ws_size,
                              hipStream_t stream) {
    const float* X      = (const float*)d_in[0];
    const float* Mask   = (const float*)d_in[1];
    const float* Delta  = (const float*)d_in[2];
    const float* x_mean = (const float*)d_in[3];
    const float* w_dg_x = (const float*)d_in[4];
    const float* b_dg_x = (const float*)d_in[5];
    const float* w_dg_h = (const float*)d_in[6];
    const float* b_dg_h = (const float*)d_in[7];
    const float* w_xz   = (const float*)d_in[8];
    const float* u_hz   = (const float*)d_in[9];
    const float* b_z    = (const float*)d_in[10];
    const float* w_xr   = (const float*)d_in[11];
    const float* u_hr   = (const float*)d_in[12];
    const float* b_r    = (const float*)d_in[13];
    const float* w_xh   = (const float*)d_in[14];
    const float* u_hh   = (const float*)d_in[15];
    const float* v_mh   = (const float*)d_in[16];
    const float* b_h    = (const float*)d_in[17];
    float* out = (float*)d_out;

    grud_kernel<<<BB, 256, 0, stream>>>(
        X, Mask, Delta, x_mean, w_dg_x, b_dg_x, w_dg_h, b_dg_h,
        w_xz, u_hz, b_z, w_xr, u_hr, b_r, w_xh, u_hh, v_mh, b_h, out);
}

// Round 4
// 423.343 us; speedup vs baseline: 1.0203x; 1.0203x over previous
//
#include <hip/hip_runtime.h>
#include <math.h>

// GRU-D, diagonal weights: independent scalar recurrence per (b,f) over T.
// R5: R2/R4 proved the compiler dissolves a source-level register double
// buffer regardless of sched_barrier placement (VGPR=64 both times; dur
// 167-185us, all pipes <30%). Escape hatch per the AITER/HK pattern: issue
// the streaming loads as inline-asm global_load_dword (volatile asm is
// never reordered against other volatile asm) and hand-place counted
// s_waitcnt vmcnt(N) -- never 0 -- so two chunks of loads (48 x 256B/wave)
// stay in flight across every phase. sched_barrier(0) after each wait
// (rule: VALU reading asm-def regs can otherwise hoist above an asm wait)
// and after each issue cluster (pins the phase's stores so the vmcnt
// arithmetic stays exact).
//
// Steady-state phase c: [s_waitcnt vmcnt(32)] [compute chunk c: 8 nt-stores]
// [issue 24 loads for chunk c+2]. Outstanding newer than chunk c's loads =
// 8 stores + 24 loads = 32. CH=8 keeps the count <= 63 (6-bit field).

#define TT 512
#define BB 256
#define FF 256
#define BF (BB * FF)        // elements per time step per array
#define CH 8                // steps per register chunk
#define NCH (TT / CH)       // 64 chunks

__device__ __forceinline__ float fast_sigmoid(float x) {
    return __builtin_amdgcn_rcpf(1.0f + __expf(-x));
}
__device__ __forceinline__ float fast_tanh(float x) {
    return fmaf(-2.0f, __builtin_amdgcn_rcpf(1.0f + __expf(2.0f * x)), 1.0f);
}

// Streaming load the compiler cannot sink: volatile asm, ordered against
// all other volatile asm (the waits). Result register is tracked by data
// flow; completion is guaranteed only by our manual vmcnt waits.
__device__ __forceinline__ float ldg_async(const float* p) {
    float r;
    asm volatile("global_load_dword %0, %1, off" : "=v"(r) : "v"(p));
    return r;
}

// Counted wait + scheduler fence (rule #18: the fence is mandatory).
#define VMWAIT(N)                                                   \
    do {                                                            \
        asm volatile("s_waitcnt vmcnt(" #N ")" ::: "memory");       \
        __builtin_amdgcn_sched_barrier(0);                          \
    } while (0)

__global__ __launch_bounds__(256, 1) void grud_kernel(
    const float* __restrict__ X, const float* __restrict__ Mask,
    const float* __restrict__ Delta,
    const float* __restrict__ x_mean,
    const float* __restrict__ w_dg_x, const float* __restrict__ b_dg_x,
    const float* __restrict__ w_dg_h, const float* __restrict__ b_dg_h,
    const float* __restrict__ w_xz, const float* __restrict__ u_hz,
    const float* __restrict__ b_z,
    const float* __restrict__ w_xr, const float* __restrict__ u_hr,
    const float* __restrict__ b_r,
    const float* __restrict__ w_xh, const float* __restrict__ u_hh,
    const float* __restrict__ v_mh, const float* __restrict__ b_h,
    float* __restrict__ out)
{
    const int f = threadIdx.x;          // 0..255 : feature index
    const int b = blockIdx.x;           // batch index

    const size_t base = (size_t)b * FF + f;
    const float* __restrict__ px = X     + base;
    const float* __restrict__ pm = Mask  + base;
    const float* __restrict__ pd = Delta + base;
    float* __restrict__ ob = out + (size_t)b * TT * FF + f;

    // per-feature parameters (coalesced, loaded once)
    const float xm  = x_mean[f];
    const float wdx = w_dg_x[f], bdx = b_dg_x[f];
    const float wdh = w_dg_h[f], bdh = b_dg_h[f];
    const float wxz = w_xz[f],   uhz = u_hz[f], bz = b_z[f];
    const float wxr = w_xr[f],   uhr = u_hr[f], br = b_r[f];
    const float wxh = w_xh[f],   uhh = u_hh[f];
    const float vmh = v_mh[f],   bh  = b_h[f];

    // Force the compiler's own waitcnt for the param loads to resolve HERE,
    // in the prologue, so no tracked-load wait lands inside the loop where
    // it would drain our untracked asm loads every iteration.
    asm volatile("" :: "v"(xm), "v"(wdx), "v"(bdx), "v"(wdh), "v"(bdh),
                       "v"(wxz), "v"(uhz), "v"(bz), "v"(wxr), "v"(uhr),
                       "v"(br), "v"(wxh), "v"(uhh), "v"(vmh), "v"(bh));

    // two register chunk-buffers (2 * 3 * 8 = 48 VGPRs of payload)
    float ax[CH], am[CH], ad[CH];
    float ex[CH], em[CH], ed[CH];
    float h = 0.0f;

    auto issuec = [&](float (&dx)[CH], float (&dm)[CH], float (&dd)[CH], int k0) {
        const size_t o = (size_t)k0 * CH * BF;
        #pragma unroll
        for (int s = 0; s < CH; ++s) dx[s] = ldg_async(px + o + (size_t)s * BF);
        #pragma unroll
        for (int s = 0; s < CH; ++s) dm[s] = ldg_async(pm + o + (size_t)s * BF);
        #pragma unroll
        for (int s = 0; s < CH; ++s) dd[s] = ldg_async(pd + o + (size_t)s * BF);
        __builtin_amdgcn_sched_barrier(0);
    };

    auto computec = [&](float (&dx)[CH], float (&dm)[CH], float (&dd)[CH], int k0) {
        float* op = ob + (size_t)k0 * CH * FF;
        #pragma unroll
        for (int s = 0; s < CH; ++s) {
            float x = dx[s], m = dm[s], d = dd[s];
            float gx = __expf(-fmaxf(0.0f, fmaf(wdx, d, bdx)));
            float gh = __expf(-fmaxf(0.0f, fmaf(wdh, d, bdh)));
            float xhat = fmaf(gx, x, (1.0f - gx) * xm);
            x = fmaf(m, x, (1.0f - m) * xhat);
            h = gh * h;
            float z  = fast_sigmoid(fmaf(wxz, x, fmaf(uhz, h, bz)));
            float r  = fast_sigmoid(fmaf(wxr, x, fmaf(uhr, h, br)));
            float ht = fast_tanh(fmaf(wxh, x, fmaf(uhh, r * h, fmaf(vmh, m, bh))));
            h = fmaf(z, ht - h, h);               // (1-z)*h + z*ht
            __builtin_nontemporal_store(h, op + (size_t)s * FF);
        }
    };

    // ---- prologue: two chunks in flight (48 loads outstanding) ----
    issuec(ax, am, ad, 0);      // chunk 0 -> A
    issuec(ex, em, ed, 1);      // chunk 1 -> B

    // phase 0 (A): only B's 24 loads are newer than chunk 0's
    VMWAIT(24);
    computec(ax, am, ad, 0);
    issuec(ax, am, ad, 2);

    // ---- steady state: chunks 1..60, uniform vmcnt(32) ----
    // at each wait: newer = 8 stores (prev phase) + 24 loads (prev issue)
    for (int c = 1; c <= NCH - 5; c += 2) {      // c = 1,3,...,59
        VMWAIT(32);
        computec(ex, em, ed, c);
        issuec(ex, em, ed, c + 2);               // <= 61, odd -> B
        VMWAIT(32);
        computec(ax, am, ad, c + 1);
        issuec(ax, am, ad, c + 3);               // <= 62, even -> A
    }

    // ---- tail: chunks 61, 62, 63 ----
    VMWAIT(32);                                  // newer: st(60) 8 + ld(62) 24
    computec(ex, em, ed, NCH - 3);               // 61
    issuec(ex, em, ed, NCH - 1);                 // 63 -> B
    VMWAIT(32);                                  // newer: st(61) 8 + ld(63) 24
    computec(ax, am, ad, NCH - 2);               // 62
    VMWAIT(8);                                   // newer: st(62) 8
    computec(ex, em, ed, NCH - 1);               // 63

    // second output: last hidden state [B, H]
    out[(size_t)BB * TT * FF + (size_t)b * FF + f] = h;
}

extern "C" void kernel_launch(void* const* d_in, const int* in_sizes, int n_in,
                              void* d_out, int out_size, void* d_ws, size_t ws_size,
                              hipStream_t stream) {
    const float* X      = (const float*)d_in[0];
    const float* Mask   = (const float*)d_in[1];
    const float* Delta  = (const float*)d_in[2];
    const float* x_mean = (const float*)d_in[3];
    const float* w_dg_x = (const float*)d_in[4];
    const float* b_dg_x = (const float*)d_in[5];
    const float* w_dg_h = (const float*)d_in[6];
    const float* b_dg_h = (const float*)d_in[7];
    const float* w_xz   = (const float*)d_in[8];
    const float* u_hz   = (const float*)d_in[9];
    const float* b_z    = (const float*)d_in[10];
    const float* w_xr   = (const float*)d_in[11];
    const float* u_hr   = (const float*)d_in[12];
    const float* b_r    = (const float*)d_in[13];
    const float* w_xh   = (const float*)d_in[14];
    const float* u_hh   = (const float*)d_in[15];
    const float* v_mh   = (const float*)d_in[16];
    const float* b_h    = (const float*)d_in[17];
    float* out = (float*)d_out;

    grud_kernel<<<BB, 256, 0, stream>>>(
        X, Mask, Delta, x_mean, w_dg_x, b_dg_x, w_dg_h, b_dg_h,
        w_xz, u_hz, b_z, w_xr, u_hr, b_r, w_xh, u_hh, v_mh, b_h, out);
}